// Round 2
// baseline (235.537 us; speedup 1.0000x reference)
//
#include <hip/hip_runtime.h>
#include <math.h>

// SPGG Fermi update, L=4096 periodic lattice.
// Exact replication of the reference f32 op order; the Fermi decision uses a
// fast f32 exp with a conservative uncertainty band, falling back to the
// bit-exact (f64 exp rounded to f32) path only when lp is within ~1e-4
// relative of the adoption threshold (~2e-4 of sites).

#define LSZ 4096
#define LMASK 4095

__global__ __launch_bounds__(256) void spgg_fermi_kernel(
    const float* __restrict__ t,       // type matrix, 0.0/1.0
    const float* __restrict__ lp,      // learning probabilities
    const int*   __restrict__ dir,     // learning direction 0..3
    float* __restrict__ out)
{
    __shared__ float c_s[38][40];   // t values, halo 3
    __shared__ float a_s[36][40];   // a = (coop_num/5)*3, halo 2 (offset by 1 in c-coords)
    __shared__ float p_s[34][40];   // profit, halo 1 (offset by 2 in c-coords)

    const int bx = blockIdx.x * 32;
    const int by = blockIdx.y * 32;
    const int tx = threadIdx.x;     // 0..31
    const int ty = threadIdx.y;     // 0..7

    // ---- prefetch decision-phase inputs early (latency hides under LDS phases) ----
    int   dirv[4];
    float lpv[4];
    const int gc = bx + tx;
    #pragma unroll
    for (int k = 0; k < 4; ++k) {
        const int gi = (by + ty + 8 * k) * LSZ + gc;
        dirv[k] = dir[gi];
        lpv[k]  = lp[gi];
    }

    // ---- stage t tile (38x38 with wrap), 2D loop: no integer division ----
    #pragma unroll
    for (int r0 = 0; r0 < 40; r0 += 8) {
        const int r = r0 + ty;
        if (r < 38) {
            const int grow = ((by + r - 3) & LMASK) * LSZ;
            c_s[r][tx] = t[grow + ((bx + tx - 3) & LMASK)];
            if (tx < 6)
                c_s[r][tx + 32] = t[grow + ((bx + tx + 29) & LMASK)];
        }
    }
    __syncthreads();

    // ---- a = (coop_num/5)*3 over 36x36 (c-coords 1..36) ----
    // coop_num n is an exact small integer 0..5; n*0.2f*3.0f is bit-identical
    // to n/5.0f*3.0f for all n in {0..5} (verified per-value).
    auto calcA = [&](int r, int c) {   // r,c are a_s coords (0..35)
        float n1 = (((c_s[r + 1][c + 1] + c_s[r][c + 1]) + c_s[r + 2][c + 1])
                    + c_s[r + 1][c]) + c_s[r + 1][c + 2];
        a_s[r][c] = n1 * 0.2f * 3.0f;
    };
    #pragma unroll
    for (int r0 = 0; r0 < 40; r0 += 8) {
        const int r = r0 + ty;
        if (r < 36) {
            calcA(r, tx);
            if (tx < 4) calcA(r, tx + 32);
        }
    }
    __syncthreads();

    // ---- profit over 34x34 (c-coords 2..35) ----
    auto calcP = [&](int r, int c) {   // r,c are p_s coords (0..33)
        float ac = a_s[r + 1][c + 1];
        float au = a_s[r][c + 1];
        float ad = a_s[r + 2][c + 1];
        float al = a_s[r + 1][c];
        float ar = a_s[r + 1][c + 2];
        float d5 = (((ac + au) + ad) + al) + ar;
        float c5 = ((((ac - 1.0f) + (au - 1.0f)) + (ad - 1.0f))
                    + (al - 1.0f)) + (ar - 1.0f);
        p_s[r][c] = (c_s[r + 2][c + 2] == 1.0f) ? c5 : d5;
    };
    #pragma unroll
    for (int r0 = 0; r0 < 40; r0 += 8) {
        const int r = r0 + ty;
        if (r < 34) {
            calcP(r, tx);
            if (tx < 2) calcP(r, tx + 32);
        }
    }
    __syncthreads();

    // ---- Fermi decision on the 32x32 inner tile ----
    #pragma unroll
    for (int k = 0; k < 4; ++k) {
        const int y = ty + 8 * k;         // output row in tile, 0..31
        const int kd = dirv[k];
        // k=0: left (j-1), 1: right (j+1), 2: up (i-1), 3: down (i+1)
        const int dr = (kd == 2) ? -1 : (kd == 3) ? 1 : 0;
        const int dc = (kd == 0) ? -1 : (kd == 1) ? 1 : 0;

        const float pc = p_s[y + 1][tx + 1];
        const float pn = p_s[y + 1 + dr][tx + 1 + dc];
        const float tc = c_s[y + 3][tx + 3];
        const float tn = c_s[y + 3 + dr][tx + 3 + dc];
        const float lpx = lpv[k];

        const float d   = pc - pn;
        // fast path: arg ~= d/0.1f (rel diff 1.5e-8), fast exp, fast rcp
        const float ef = __expf(d * 10.0f);
        const float Wf = __builtin_amdgcn_rcpf(1.0f + ef);
        const float eps = 1e-4f * Wf + 1e-37f;

        float res;
        if (lpx <= Wf - eps) {            // certainly adopt
            res = tn;
        } else if (lpx > Wf + eps) {      // certainly reject
            res = tc;
        } else {
            // bit-exact reference path (matches round-1, absmax 0.0)
            const float arg = d / 0.1f;
            const float e = (float)exp((double)arg);
            const float W = 1.0f / (1.0f + e);
            res = (lpx <= W) ? tn : tc;
        }
        out[(by + y) * LSZ + gc] = res;
    }
}

extern "C" void kernel_launch(void* const* d_in, const int* in_sizes, int n_in,
                              void* d_out, int out_size, void* d_ws, size_t ws_size,
                              hipStream_t stream)
{
    const float* t   = (const float*)d_in[0];
    const float* lp  = (const float*)d_in[1];
    const int*   dir = (const int*)d_in[2];
    float* out = (float*)d_out;

    dim3 grid(LSZ / 32, LSZ / 32);   // 128 x 128 blocks
    dim3 block(32, 8);
    hipLaunchKernelGGL(spgg_fermi_kernel, grid, block, 0, stream, t, lp, dir, out);
}

// Round 5
// 229.657 us; speedup vs baseline: 1.0256x; 1.0256x over previous
//
#include <hip/hip_runtime.h>
#include <math.h>

// SPGG Fermi update, L=4096 periodic lattice — register-streaming version.
// Each wave owns a 256-col strip (4 cols/lane, float4); rows stream with
// t/a/p register history; horizontal neighbors via ds_bpermute shuffles.
// No LDS planes, no barriers. f32 op order identical to the verified
// round-2 kernel (absmax 0.0): n*0.2f*3.0f, same sum association, same
// fast-exp + exact-fallback Fermi band.

#define LSZ 4096
#define LMASK 4095
#define STRIPS 18        // 18 * 232 = 4176 >= 4096 (overlap writes identical values)
#define OUTW 232         // valid output cols per strip (lanes 3..60)
#define BANDS 256        // 4096 / 16
#define BANDH 16

__device__ __forceinline__ float4 a_row(float4 tm, float4 tc, float4 tp,
                                        int lm1, int lp1, float& tl, float& tr) {
    tl = __shfl(tc.w, lm1);
    tr = __shfl(tc.x, lp1);
    float4 n, a;
    // reference order: ((((center + up) + down) + left) + right)
    n.x = (((tc.x + tm.x) + tp.x) + tl)   + tc.y;
    n.y = (((tc.y + tm.y) + tp.y) + tc.x) + tc.z;
    n.z = (((tc.z + tm.z) + tp.z) + tc.y) + tc.w;
    n.w = (((tc.w + tm.w) + tp.w) + tc.z) + tr;
    // n*0.2f*3.0f bit-identical to n/5.0f*3.0f for n in {0..5}
    a.x = n.x * 0.2f * 3.0f;
    a.y = n.y * 0.2f * 3.0f;
    a.z = n.z * 0.2f * 3.0f;
    a.w = n.w * 0.2f * 3.0f;
    return a;
}

__device__ __forceinline__ float4 p_row(float4 am, float4 ac, float4 ap, float4 tc,
                                        int lm1, int lp1) {
    float al = __shfl(ac.w, lm1);
    float ar = __shfl(ac.x, lp1);
    float4 p;
    {
        float d5 = (((ac.x + am.x) + ap.x) + al) + ac.y;
        float c5 = ((((ac.x - 1.0f) + (am.x - 1.0f)) + (ap.x - 1.0f)) + (al - 1.0f)) + (ac.y - 1.0f);
        p.x = (tc.x == 1.0f) ? c5 : d5;
    }
    {
        float d5 = (((ac.y + am.y) + ap.y) + ac.x) + ac.z;
        float c5 = ((((ac.y - 1.0f) + (am.y - 1.0f)) + (ap.y - 1.0f)) + (ac.x - 1.0f)) + (ac.z - 1.0f);
        p.y = (tc.y == 1.0f) ? c5 : d5;
    }
    {
        float d5 = (((ac.z + am.z) + ap.z) + ac.y) + ac.w;
        float c5 = ((((ac.z - 1.0f) + (am.z - 1.0f)) + (ap.z - 1.0f)) + (ac.y - 1.0f)) + (ac.w - 1.0f);
        p.z = (tc.z == 1.0f) ? c5 : d5;
    }
    {
        float d5 = (((ac.w + am.w) + ap.w) + ac.z) + ar;
        float c5 = ((((ac.w - 1.0f) + (am.w - 1.0f)) + (ap.w - 1.0f)) + (ac.z - 1.0f)) + (ar - 1.0f);
        p.w = (tc.w == 1.0f) ? c5 : d5;
    }
    return p;
}

__device__ __forceinline__ float fermi(float pc, float pnl, float pnr, float pnu, float pnd,
                                       float tc, float tnl, float tnr, float tnu, float tnd,
                                       float lpx, int k) {
    float pn = (k == 0) ? pnl : (k == 1) ? pnr : (k == 2) ? pnu : pnd;
    float tn = (k == 0) ? tnl : (k == 1) ? tnr : (k == 2) ? tnu : tnd;
    float d  = pc - pn;
    // fast path (rel err ~1e-5) with conservative uncertainty band
    float ef = __expf(d * 10.0f);
    float Wf = __builtin_amdgcn_rcpf(1.0f + ef);
    float eps = 1e-4f * Wf + 1e-37f;
    float res;
    if (lpx <= Wf - eps)      res = tn;
    else if (lpx > Wf + eps)  res = tc;
    else {
        // bit-exact reference path (verified absmax 0.0 in rounds 1-2)
        float arg = d / 0.1f;
        float e = (float)exp((double)arg);
        float W = 1.0f / (1.0f + e);
        res = (lpx <= W) ? tn : tc;
    }
    return res;
}

__global__ __launch_bounds__(256) void spgg_fermi_kernel(
    const float* __restrict__ t,       // type matrix, 0.0/1.0
    const float* __restrict__ lp,      // learning probabilities
    const int*   __restrict__ dir,     // learning direction 0..3
    float* __restrict__ out)
{
    const int lane = threadIdx.x & 63;
    const int wv   = threadIdx.x >> 6;
    const int s    = blockIdx.x >> 6;          // strip 0..17
    const int bg   = blockIdx.x & 63;          // band group 0..63
    const int band = bg * 4 + wv;              // 0..255 (consecutive bands share halo in L1/L2)
    const int r0   = band * BANDH;
    const int cb   = s * OUTW - 12;            // lane-0 col of this strip
    const int col  = (cb + 4 * lane) & LMASK;  // 16B-aligned, wrapped
    const int lm1  = (lane + 63) & 63;
    const int lp1  = (lane + 1) & 63;
    const bool valid = (lane >= 3) && (lane <= 60);

    auto ldT  = [&](int r_) -> float4 { return *(const float4*)&t  [((r_ & LMASK) << 12) + col]; };
    auto ldLP = [&](int r_) -> float4 { return *(const float4*)&lp [((r_ & LMASK) << 12) + col]; };
    auto ldDR = [&](int r_) -> int4   { return *(const int4*)  &dir[((r_ & LMASK) << 12) + col]; };

    // ---- warmup: fill the pipeline for out row r0 ----
    float4 u0 = ldT(r0 - 3), u1 = ldT(r0 - 2), u2 = ldT(r0 - 1), u3 = ldT(r0);
    float4 u4 = ldT(r0 + 1), u5 = ldT(r0 + 2), u6 = ldT(r0 + 3);

    float tlA, trA, tlB, trB, tlC, trC, tsc;
    float4 aM2 = a_row(u0, u1, u2, lm1, lp1, tlC, tsc);   // a(r0-2), edges discarded
    trC = tsc;
    float4 aM1 = a_row(u1, u2, u3, lm1, lp1, tlC, trC);   // a(r0-1), discarded
    float4 A0  = a_row(u2, u3, u4, lm1, lp1, tlA, trA);   // a(r0), keep t-edges of row r0
    float4 A1  = a_row(u3, u4, u5, lm1, lp1, tlB, trB);   // a(r0+1), keep t-edges of row r0+1
    float4 P0  = p_row(aM2, aM1, A0, u2, lm1, lp1);       // p(r0-1)
    float4 P1  = p_row(aM1, A0, A1, u3, lm1, lp1);        // p(r0)

    float4 T0 = u2, T1 = u3, T2 = u4, T3 = u5, T4 = u6;   // t(r-1 .. r+3)
    float4 LPc = ldLP(r0);
    int4   DRc = ldDR(r0);

    // ---- main loop: one output row per iteration ----
    #pragma unroll 4
    for (int i = 0; i < BANDH; ++i) {
        const int r = r0 + i;

        // prefetch next iteration's inputs (1 full row of latency hiding)
        float4 Tn  = ldT(r + 4);
        float4 LPn = ldLP(r + 1);
        int4   DRn = ldDR(r + 1);

        float4 A2 = a_row(T2, T3, T4, lm1, lp1, tlC, trC);  // a(r+2), t-edges of row r+2
        float4 P2 = p_row(A0, A1, A2, T2, lm1, lp1);        // p(r+1)

        float plx = __shfl(P1.w, lm1);
        float prx = __shfl(P1.x, lp1);

        float4 o;
        o.x = fermi(P1.x, plx,  P1.y, P0.x, P2.x, T1.x, tlA,  T1.y, T0.x, T2.x, LPc.x, DRc.x);
        o.y = fermi(P1.y, P1.x, P1.z, P0.y, P2.y, T1.y, T1.x, T1.z, T0.y, T2.y, LPc.y, DRc.y);
        o.z = fermi(P1.z, P1.y, P1.w, P0.z, P2.z, T1.z, T1.y, T1.w, T0.z, T2.z, LPc.z, DRc.z);
        o.w = fermi(P1.w, P1.z, prx,  P0.w, P2.w, T1.w, T1.z, trA,  T0.w, T2.w, LPc.w, DRc.w);

        if (valid) *(float4*)&out[(r << 12) + col] = o;

        // rotate pipeline state
        T0 = T1; T1 = T2; T2 = T3; T3 = T4; T4 = Tn;
        A0 = A1; A1 = A2;
        P0 = P1; P1 = P2;
        tlA = tlB; trA = trB; tlB = tlC; trB = trC;
        LPc = LPn; DRc = DRn;
    }
}

extern "C" void kernel_launch(void* const* d_in, const int* in_sizes, int n_in,
                              void* d_out, int out_size, void* d_ws, size_t ws_size,
                              hipStream_t stream)
{
    const float* t   = (const float*)d_in[0];
    const float* lp  = (const float*)d_in[1];
    const int*   dir = (const int*)d_in[2];
    float* out = (float*)d_out;

    // 18 strips x 64 band-groups; each block = 4 waves = 4 vertical bands
    dim3 grid(STRIPS * 64);
    dim3 block(256);
    hipLaunchKernelGGL(spgg_fermi_kernel, grid, block, 0, stream, t, lp, dir, out);
}